// Round 1
// baseline (2693.871 us; speedup 1.0000x reference)
//
#include <hip/hip_runtime.h>
#include <hip/hip_bf16.h>
#include <math.h>

// Problem constants (fixed by the reference)
#define BB    512
#define NPG   34
#define NT    17408      // BB*NPG
#define FEAT  1152
#define GPD   2048
#define HID   1024
#define NH    8
#define AD    64
#define HA    512        // NH*AD
#define LLM   4096
#define EPG   272        // 34*8
#define NE    139264     // BB*EPG
#define C32   24576      // 32*768
#define CC    768

// ---------------- pool: [B,768,8,8,4] -> [B,24576] (2x2x2 mean) ----------------
__global__ __launch_bounds__(256) void k_pool(const float* __restrict__ gf, float* __restrict__ out) {
    int t = blockIdx.x * 256 + threadIdx.x;     // over B*C*16 = 6,291,456
    int q = t & 15; int bc = t >> 4;            // bc = b*768 + c
    int dO = q >> 2, hO = q & 3;
    const float* p = gf + (size_t)bc * 256 + dO * 64 + hO * 8;
    float4 r00 = *(const float4*)(p);
    float4 r01 = *(const float4*)(p + 4);
    float4 r10 = *(const float4*)(p + 32);
    float4 r11 = *(const float4*)(p + 36);
    float o0 = (r00.x + r00.y + r01.x + r01.y + r10.x + r10.y + r11.x + r11.y) * 0.125f;
    float o1 = (r00.z + r00.w + r01.z + r01.w + r10.z + r10.w + r11.z + r11.w) * 0.125f;
    int b = bc / CC, c = bc % CC;
    float* o = out + (size_t)b * C32 + c * 32 + dO * 8 + hO * 2;
    o[0] = o0; o[1] = o1;
}

// ---------------- 64x64 tile fp32 GEMM (split-K capable, raw partial output) ----------------
__global__ __launch_bounds__(256) void k_gemm64(
    const float* __restrict__ A, const float* __restrict__ Bw, float* __restrict__ Cp,
    int M, int N, int K, int kChunk) {
    __shared__ float As[32 * 64];
    __shared__ float Bs[32 * 64];
    int t = threadIdx.x;
    int n0 = blockIdx.x * 64, m0 = blockIdx.y * 64;
    int sk = blockIdx.z;
    int k0 = sk * kChunk, k1 = k0 + kChunk;
    int tm = t >> 4, tn = t & 15;

    // hoisted staging geometry (p = 0,1)
    const float* aptr[2]; const float* bptr[2];
    int am[2], akq[2], bkb[2], bnq[2];
#pragma unroll
    for (int p = 0; p < 2; p++) {
        int q = t + p * 256;
        am[p] = q >> 3; akq[p] = (q & 7) << 2;
        aptr[p] = A + (size_t)(m0 + am[p]) * K + akq[p];
        bkb[p] = q >> 4; bnq[p] = (q & 15) << 2;
        bptr[p] = Bw + (size_t)bkb[p] * N + n0 + bnq[p];
    }

    float acc[4][4] = {};
    for (int kk = k0; kk < k1; kk += 32) {
        __syncthreads();
#pragma unroll
        for (int p = 0; p < 2; p++) {
            float4 v = *(const float4*)(aptr[p] + kk);
            As[(akq[p] + 0) * 64 + am[p]] = v.x;
            As[(akq[p] + 1) * 64 + am[p]] = v.y;
            As[(akq[p] + 2) * 64 + am[p]] = v.z;
            As[(akq[p] + 3) * 64 + am[p]] = v.w;
            *(float4*)&Bs[bkb[p] * 64 + bnq[p]] = *(const float4*)(bptr[p] + (size_t)kk * N);
        }
        __syncthreads();
#pragma unroll
        for (int k = 0; k < 32; k++) {
            float4 a = *(float4*)&As[k * 64 + tm * 4];
            float4 b = *(float4*)&Bs[k * 64 + tn * 4];
            float av[4] = {a.x, a.y, a.z, a.w};
            float bv[4] = {b.x, b.y, b.z, b.w};
#pragma unroll
            for (int i = 0; i < 4; i++)
#pragma unroll
                for (int j = 0; j < 4; j++)
                    acc[i][j] = fmaf(av[i], bv[j], acc[i][j]);
        }
    }
    float* cp = Cp + (size_t)sk * M * N;
#pragma unroll
    for (int i = 0; i < 4; i++) {
        float4 v = {acc[i][0], acc[i][1], acc[i][2], acc[i][3]};
        *(float4*)(cp + (size_t)(m0 + tm * 4 + i) * N + n0 + tn * 4) = v;
    }
}

// ---------------- reduce split-K partials + bias + relu -> g1 ----------------
__global__ __launch_bounds__(256) void k_red1(const float* __restrict__ part,
                                              const float* __restrict__ b1g,
                                              float* __restrict__ g1) {
    int i = blockIdx.x * 256 + threadIdx.x;     // over 512*2048
    float s = b1g[i & (GPD - 1)];
    s += part[i] + part[i + 1048576] + part[i + 2 * 1048576] + part[i + 3 * 1048576];
    g1[i] = s > 0.f ? s : 0.f;
}

// ---------------- 128x128 tile fp32 GEMM, optional node-gather A, bias, relu ----------------
template<bool GATHER, bool OBIAS, bool ORELU>
__global__ __launch_bounds__(256) void k_gemm128(
    const float* __restrict__ A, const float* __restrict__ Bw,
    const float* __restrict__ obias, float* __restrict__ C,
    int M, int N, int K,
    const float* __restrict__ outg, const float* __restrict__ b2g,
    const float* __restrict__ locf) {
    __shared__ float As[16 * 132];   // padded stride 132 to soften write conflicts
    __shared__ float Bs[16 * 128];
    int t = threadIdx.x;
    int n0 = blockIdx.x * 128, m0 = blockIdx.y * 128;
    int tm = t >> 4, tn = t & 15;

    const float* aptr[2]; bool aAddB[2];
    int am[2], akq[2];
    const float* bptr[2]; int bkb[2], bnq[2];
#pragma unroll
    for (int p = 0; p < 2; p++) {
        int q = t + p * 256;
        am[p] = q >> 2; akq[p] = (q & 3) << 2;
        int row = m0 + am[p];
        if (GATHER) {
            int b = row / NPG, j = row % NPG;
            if (j == 0) { aptr[p] = outg + (size_t)b * FEAT + akq[p]; aAddB[p] = true; }
            else        { aptr[p] = locf + ((size_t)b * 33 + (j - 1)) * FEAT + akq[p]; aAddB[p] = false; }
        } else {
            aptr[p] = A + (size_t)row * K + akq[p]; aAddB[p] = false;
        }
        bkb[p] = q >> 5; bnq[p] = (q & 31) << 2;
        bptr[p] = Bw + (size_t)bkb[p] * N + n0 + bnq[p];
    }

    float acc[8][8] = {};
    for (int kk = 0; kk < K; kk += 16) {
        __syncthreads();
#pragma unroll
        for (int p = 0; p < 2; p++) {
            float4 v = *(const float4*)(aptr[p] + kk);
            if (GATHER && aAddB[p]) {
                float4 bb = *(const float4*)(b2g + kk + akq[p]);
                v.x += bb.x; v.y += bb.y; v.z += bb.z; v.w += bb.w;
            }
            As[(akq[p] + 0) * 132 + am[p]] = v.x;
            As[(akq[p] + 1) * 132 + am[p]] = v.y;
            As[(akq[p] + 2) * 132 + am[p]] = v.z;
            As[(akq[p] + 3) * 132 + am[p]] = v.w;
            *(float4*)&Bs[bkb[p] * 128 + bnq[p]] = *(const float4*)(bptr[p] + (size_t)kk * N);
        }
        __syncthreads();
#pragma unroll
        for (int k = 0; k < 16; k++) {
            float4 a0 = *(float4*)&As[k * 132 + tm * 8];
            float4 a1 = *(float4*)&As[k * 132 + tm * 8 + 4];
            float4 b0 = *(float4*)&Bs[k * 128 + tn * 8];
            float4 b1 = *(float4*)&Bs[k * 128 + tn * 8 + 4];
            float av[8] = {a0.x, a0.y, a0.z, a0.w, a1.x, a1.y, a1.z, a1.w};
            float bv[8] = {b0.x, b0.y, b0.z, b0.w, b1.x, b1.y, b1.z, b1.w};
#pragma unroll
            for (int i = 0; i < 8; i++)
#pragma unroll
                for (int j = 0; j < 8; j++)
                    acc[i][j] = fmaf(av[i], bv[j], acc[i][j]);
        }
    }
#pragma unroll
    for (int i = 0; i < 8; i++) {
        int row = m0 + tm * 8 + i;
#pragma unroll
        for (int jj = 0; jj < 8; jj += 4) {
            float4 v = {acc[i][jj], acc[i][jj + 1], acc[i][jj + 2], acc[i][jj + 3]};
            if (OBIAS) {
                float4 bb = *(const float4*)(obias + n0 + tn * 8 + jj);
                v.x += bb.x; v.y += bb.y; v.z += bb.z; v.w += bb.w;
            }
            if (ORELU) {
                v.x = v.x > 0.f ? v.x : 0.f; v.y = v.y > 0.f ? v.y : 0.f;
                v.z = v.z > 0.f ? v.z : 0.f; v.w = v.w > 0.f ? v.w : 0.f;
            }
            *(float4*)(C + (size_t)row * N + n0 + tn * 8 + jj) = v;
        }
    }
}

// ---------------- per-node attention scores ps/pd [NT,8] ----------------
__global__ __launch_bounds__(256) void k_scores(const float* __restrict__ z,
                                                const float* __restrict__ a_src,
                                                const float* __restrict__ a_dst,
                                                float* __restrict__ ps, float* __restrict__ pd) {
    int wave = threadIdx.x >> 6, l = threadIdx.x & 63;
    int n = blockIdx.x * 4 + wave;
    const float* zr = z + (size_t)n * HA;
    float s[NH], d[NH];
#pragma unroll
    for (int i = 0; i < NH; i++) {
        float zv = zr[i * 64 + l];
        s[i] = zv * a_src[i * 64 + l];
        d[i] = zv * a_dst[i * 64 + l];
    }
#pragma unroll
    for (int i = 0; i < NH; i++) {
#pragma unroll
        for (int off = 32; off > 0; off >>= 1) {
            s[i] += __shfl_xor(s[i], off);
            d[i] += __shfl_xor(d[i], off);
        }
    }
    if (l == 0) {
#pragma unroll
        for (int i = 0; i < NH; i++) {
            ps[(size_t)n * NH + i] = s[i];
            pd[(size_t)n * NH + i] = d[i];
        }
    }
}

// ---------------- per-graph edge softmax -> alpha [E,8] ----------------
__global__ __launch_bounds__(256) void k_attn(const int* __restrict__ es, const int* __restrict__ ed,
                                              const float* __restrict__ ps, const float* __restrict__ pd,
                                              float* __restrict__ alpha) {
    __shared__ float sps[EPG], spd[EPG], esc[EPG * NH], sm[NPG * NH], sden[NPG * NH];
    __shared__ int sl[EPG], dl[EPG];
    int b = blockIdx.x, t = threadIdx.x;
    for (int i = t; i < EPG; i += 256) {
        sps[i] = ps[(size_t)b * EPG + i];      // [34 nodes x 8 heads] contiguous
        spd[i] = pd[(size_t)b * EPG + i];
        sl[i] = es[b * EPG + i] - b * NPG;
        dl[i] = ed[b * EPG + i] - b * NPG;
    }
    __syncthreads();
    for (int i = t; i < EPG * NH; i += 256) {
        int e = i >> 3, h = i & 7;
        float sc = sps[sl[e] * NH + h] + spd[dl[e] * NH + h];
        esc[i] = sc > 0.f ? sc : 0.2f * sc;
    }
    __syncthreads();
    for (int i = t; i < NPG * NH; i += 256) {   // (n,h)
        int n = i >> 3, h = i & 7;
        float m = -INFINITY;
        for (int e = 0; e < EPG; e++)
            if (dl[e] == n) m = fmaxf(m, esc[e * NH + h]);
        if (m == -INFINITY) m = 0.f;
        float den = 0.f;
        for (int e = 0; e < EPG; e++)
            if (dl[e] == n) den += expf(esc[e * NH + h] - m);
        sm[i] = m; sden[i] = den;
    }
    __syncthreads();
    for (int i = t; i < EPG * NH; i += 256) {
        int e = i >> 3, h = i & 7;
        float a = expf(esc[i] - sm[dl[e] * NH + h]) / (sden[dl[e] * NH + h] + 1e-9f);
        alpha[((size_t)b * EPG + e) * NH + h] = a;
    }
}

// ---------------- aggregation: gnn[n, h*64+d] = sum_{e: dst=n} alpha[e,h]*z[src_e, h*64+d] ----------------
__global__ __launch_bounds__(256) void k_agg(const int* __restrict__ es, const int* __restrict__ ed,
                                             const float* __restrict__ alpha, const float* __restrict__ z,
                                             float* __restrict__ gnn) {
    __shared__ float zt[NPG * AD];
    __shared__ float al[EPG];
    __shared__ int srcl[EPG], dll[EPG], order[EPG], cnt[NPG], bstart[NPG + 1];
    int b = blockIdx.x >> 3, h = blockIdx.x & 7;
    int t = threadIdx.x;
    for (int i = t; i < NPG * AD; i += 256)
        zt[i] = z[((size_t)b * NPG + (i >> 6)) * HA + (h << 6) + (i & 63)];
    for (int e = t; e < EPG; e += 256) {
        srcl[e] = es[b * EPG + e] - b * NPG;
        dll[e]  = ed[b * EPG + e] - b * NPG;
        al[e]   = alpha[((size_t)b * EPG + e) * NH + h];
    }
    if (t < NPG) cnt[t] = 0;
    __syncthreads();
    for (int e = t; e < EPG; e += 256) atomicAdd(&cnt[dll[e]], 1);
    __syncthreads();
    if (t == 0) {   // deterministic serial prefix + scatter
        int s = 0;
        for (int n = 0; n < NPG; n++) { bstart[n] = s; s += cnt[n]; cnt[n] = bstart[n]; }
        bstart[NPG] = s;
        for (int e = 0; e < EPG; e++) order[cnt[dll[e]]++] = e;
    }
    __syncthreads();
    for (int i = t; i < NPG * AD; i += 256) {
        int n = i >> 6, d = i & 63;
        float acc = 0.f;
        for (int j = bstart[n]; j < bstart[n + 1]; j++) {
            int e = order[j];
            acc = fmaf(al[e], zt[srcl[e] * AD + d], acc);
        }
        gnn[((size_t)b * NPG + n) * HA + (h << 6) + d] = acc;
    }
}

extern "C" void kernel_launch(void* const* d_in, const int* in_sizes, int n_in,
                              void* d_out, int out_size, void* d_ws, size_t ws_size,
                              hipStream_t stream) {
    const float* locf  = (const float*)d_in[0];
    const float* gf    = (const float*)d_in[1];
    const int*   ei    = (const int*)d_in[2];
    const float* W1g   = (const float*)d_in[3];
    const float* b1g   = (const float*)d_in[4];
    const float* W2g   = (const float*)d_in[5];
    const float* b2g   = (const float*)d_in[6];
    const float* Wp    = (const float*)d_in[7];
    const float* bp    = (const float*)d_in[8];
    const float* Wg    = (const float*)d_in[9];
    const float* a_src = (const float*)d_in[10];
    const float* a_dst = (const float*)d_in[11];
    const float* Wllm  = (const float*)d_in[12];
    const float* bllm  = (const float*)d_in[13];
    float* out = (float*)d_out;
    float* ws  = (float*)d_ws;
    const int* es = ei;
    const int* ed = ei + NE;

    // scratch inside d_out (fully rewritten by final GEMM): pool/z | h | partials
    float* pool = out;                                  // 12,582,912 f (dead after GEMM1)
    float* z    = out;                                  //  8,912,896 f (reuses pool region)
    float* h    = out + 12582912;                       // 17,825,792 f
    float* part = out + 12582912 + 17825792;            //  4,194,304 f (4 x 512x2048)
    // scratch in d_ws (47.8 MB total)
    float* g1    = ws;                                  // 1,048,576 f
    float* outg  = g1 + 1048576;                        //   589,824 f
    float* ps    = outg + 589824;                       //   139,264 f
    float* pd    = ps + 139264;                         //   139,264 f
    float* alpha = pd + 139264;                         // 1,114,112 f
    float* gnn   = alpha + 1114112;                     // 8,912,896 f

    // 1. pool
    k_pool<<<24576, 256, 0, stream>>>(gf, pool);
    // 2. GEMM1 split-K(4): [512,24576]x[24576,2048] -> partials
    k_gemm64<<<dim3(32, 8, 4), 256, 0, stream>>>(pool, W1g, part, 512, GPD, C32, 6144);
    // 3. reduce + b1g + relu -> g1
    k_red1<<<4096, 256, 0, stream>>>(part, b1g, g1);
    // 4. GEMM2: [512,2048]x[2048,1152] -> outg (b2g folded into gather below)
    k_gemm64<<<dim3(18, 8, 1), 256, 0, stream>>>(g1, W2g, outg, 512, FEAT, GPD, GPD);
    // 5. GEMM3 (gather nodes): relu(nodes x Wp + bp) -> h [17408,1024]
    k_gemm128<true, true, true><<<dim3(8, 136), 256, 0, stream>>>(
        nullptr, Wp, bp, h, NT, HID, FEAT, outg, b2g, locf);
    // 6. GEMM4: z = h x Wg [17408,512]
    k_gemm128<false, false, false><<<dim3(4, 136), 256, 0, stream>>>(
        h, Wg, nullptr, z, NT, HA, HID, nullptr, nullptr, nullptr);
    // 7. per-node scores
    k_scores<<<4352, 256, 0, stream>>>(z, a_src, a_dst, ps, pd);
    // 8. per-graph edge softmax -> alpha
    k_attn<<<BB, 256, 0, stream>>>(es, ed, ps, pd, alpha);
    // 9. aggregation -> gnn
    k_agg<<<BB * NH, 256, 0, stream>>>(es, ed, alpha, z, gnn);
    // 10. GEMM5: out = gnn x Wllm + bllm [17408,4096]
    k_gemm128<false, true, false><<<dim3(32, 136), 256, 0, stream>>>(
        gnn, Wllm, bllm, out, NT, LLM, HA, nullptr, nullptr, nullptr);
}

// Round 2
// 744.853 us; speedup vs baseline: 3.6167x; 3.6167x over previous
//
#include <hip/hip_runtime.h>
#include <hip/hip_bf16.h>
#include <math.h>

#define BB    512
#define NPG   34
#define NT    17408
#define FEAT  1152
#define GPD   2048
#define HID   1024
#define NH    8
#define AD    64
#define HA    512
#define LLM   4096
#define EPG   272
#define NE    139264
#define C32   24576
#define CC    768

#define AS3 __attribute__((address_space(3)))
#define AS1 __attribute__((address_space(1)))

typedef __attribute__((ext_vector_type(8))) short short8v;
typedef __attribute__((ext_vector_type(4))) float f32x4;

__device__ __forceinline__ ushort f2bf(float f) {
    __hip_bfloat16 h = __float2bfloat16(f);
    return __builtin_bit_cast(ushort, h);
}

// ---------------- transpose + fp32->bf16: W[R][Cn] -> WT[Cn][R] ----------------
__global__ __launch_bounds__(256) void k_transpose(const float* __restrict__ W,
                                                   ushort* __restrict__ WT, int R, int Cn) {
    __shared__ float tile[32][33];
    int c0 = blockIdx.x * 32, r0 = blockIdx.y * 32;
    int tc = threadIdx.x & 31, tr = threadIdx.x >> 5;
#pragma unroll
    for (int i = 0; i < 4; i++)
        tile[tr + i * 8][tc] = W[(size_t)(r0 + tr + i * 8) * Cn + c0 + tc];
    __syncthreads();
#pragma unroll
    for (int it = 0; it < 2; it++) {
        int p = threadIdx.x + it * 256;
        int c = p >> 4, pr = (p & 15) << 1;
        ushort2 v;
        v.x = f2bf(tile[pr][c]);
        v.y = f2bf(tile[pr + 1][c]);
        *(ushort2*)&WT[(size_t)(c0 + c) * R + r0 + pr] = v;
    }
}

// ---------------- pool: [B,768,8,8,4] -> bf16 [B,24576] (2x2x2 mean) ----------------
__global__ __launch_bounds__(256) void k_pool(const float* __restrict__ gf, ushort* __restrict__ outB) {
    int t = blockIdx.x * 256 + threadIdx.x;
    int q = t & 15; int bc = t >> 4;
    int dO = q >> 2, hO = q & 3;
    const float* p = gf + (size_t)bc * 256 + dO * 64 + hO * 8;
    float4 r00 = *(const float4*)(p);
    float4 r01 = *(const float4*)(p + 4);
    float4 r10 = *(const float4*)(p + 32);
    float4 r11 = *(const float4*)(p + 36);
    float o0 = (r00.x + r00.y + r01.x + r01.y + r10.x + r10.y + r11.x + r11.y) * 0.125f;
    float o1 = (r00.z + r00.w + r01.z + r01.w + r10.z + r10.w + r11.z + r11.w) * 0.125f;
    int b = bc / CC, c = bc % CC;
    ushort2 v; v.x = f2bf(o0); v.y = f2bf(o1);
    *(ushort2*)(outB + (size_t)b * C32 + c * 32 + dO * 8 + hO * 2) = v;
}

// ---------------- bf16 MFMA GEMM: A[M][K] x BT[N][K]^T -> C[M][N] ----------------
// 128x128 tile, BK=32, 4 waves (each 64x64), global_load_lds staging (m97 structure)
template<bool SPLITK, bool BIAS, bool RELU, bool OUTBF>
__global__ __launch_bounds__(256) void k_gemm_bf(
    const ushort* __restrict__ A, const ushort* __restrict__ BT,
    const float* __restrict__ bias, void* __restrict__ Cout,
    int M, int N, int K, int kChunk) {
    __shared__ ushort lA[128 * 32];
    __shared__ ushort lB[128 * 32];
    const int t = threadIdx.x;
    const int w = t >> 6, l = t & 63;
    const int m0 = blockIdx.y * 128, n0 = blockIdx.x * 128;
    const int kLen = SPLITK ? kChunk : K;
    const int k0 = SPLITK ? blockIdx.z * kChunk : 0;
    // staging geometry: round p (0,1), wave w: rows p*64 + w*16 + l/4, k byte-quad (l&3)*8
    const int srow = w * 16 + (l >> 2);
    const int skq = (l & 3) << 3;
    const ushort* gA = A + (size_t)(m0 + srow) * K + k0 + skq;
    const ushort* gB = BT + (size_t)(n0 + srow) * K + k0 + skq;
    ushort* lA0 = lA + w * 512;
    ushort* lB0 = lB + w * 512;
    const size_t str64 = (size_t)64 * K;
    const int wr = (w >> 1) << 6, wc = (w & 1) << 6;
    const int fcol = l & 15, fk = (l >> 4) << 3;

    f32x4 acc[4][4] = {};
    for (int kk = 0; kk < kLen; kk += 32) {
        __syncthreads();
        __builtin_amdgcn_global_load_lds((const AS1 void*)(gA + kk),         (AS3 void*)lA0,          16, 0, 0);
        __builtin_amdgcn_global_load_lds((const AS1 void*)(gA + kk + str64), (AS3 void*)(lA0 + 2048), 16, 0, 0);
        __builtin_amdgcn_global_load_lds((const AS1 void*)(gB + kk),         (AS3 void*)lB0,          16, 0, 0);
        __builtin_amdgcn_global_load_lds((const AS1 void*)(gB + kk + str64), (AS3 void*)(lB0 + 2048), 16, 0, 0);
        __syncthreads();
        short8v a[4], b[4];
#pragma unroll
        for (int f = 0; f < 4; f++) {
            a[f] = *(const short8v*)(lA + (wr + f * 16 + fcol) * 32 + fk);
            b[f] = *(const short8v*)(lB + (wc + f * 16 + fcol) * 32 + fk);
        }
#pragma unroll
        for (int i = 0; i < 4; i++)
#pragma unroll
            for (int j = 0; j < 4; j++)
                acc[i][j] = __builtin_amdgcn_mfma_f32_16x16x32_bf16(a[i], b[j], acc[i][j], 0, 0, 0);
    }
    const int orow = (l >> 4) << 2;
#pragma unroll
    for (int i = 0; i < 4; i++) {
#pragma unroll
        for (int j = 0; j < 4; j++) {
            int col = n0 + wc + j * 16 + fcol;
            float bv = BIAS ? bias[col] : 0.f;
#pragma unroll
            for (int r = 0; r < 4; r++) {
                int row = m0 + wr + i * 16 + orow + r;
                float v = acc[i][j][r] + bv;
                if (RELU) v = v > 0.f ? v : 0.f;
                if (OUTBF) {
                    ((ushort*)Cout)[(size_t)row * N + col] = f2bf(v);
                } else {
                    size_t off = (size_t)row * N + col;
                    if (SPLITK) off += (size_t)blockIdx.z * (size_t)M * N;
                    ((float*)Cout)[off] = v;
                }
            }
        }
    }
}

// ---------------- reduce GEMM1 split-K(8) partials + b1g + relu -> bf16 g1 ----------------
__global__ __launch_bounds__(256) void k_red1(const float* __restrict__ part,
                                              const float* __restrict__ b1g,
                                              ushort* __restrict__ g1B) {
    int i = blockIdx.x * 256 + threadIdx.x;   // over 512*2048
    float s = b1g[i & (GPD - 1)];
#pragma unroll
    for (int q = 0; q < 8; q++) s += part[i + q * 1048576];
    g1B[i] = f2bf(s > 0.f ? s : 0.f);
}

// ---------------- build bf16 node matrix [NT][FEAT] ----------------
__global__ __launch_bounds__(256) void k_nodes(const ushort* __restrict__ outgB,
                                               const float* __restrict__ locf,
                                               ushort* __restrict__ nodesB) {
    int node = blockIdx.x;
    int b = node / NPG, j = node % NPG;
    ushort* dst = nodesB + (size_t)node * FEAT;
    if (threadIdx.x < 144) {
        int c = threadIdx.x * 8;
        if (j == 0) {
            *(uint4*)(dst + c) = *(const uint4*)(outgB + (size_t)b * FEAT + c);
        } else {
            const float* s = locf + ((size_t)b * 33 + (j - 1)) * FEAT + c;
            float4 v0 = *(const float4*)s, v1 = *(const float4*)(s + 4);
            ushort u[8] = {f2bf(v0.x), f2bf(v0.y), f2bf(v0.z), f2bf(v0.w),
                           f2bf(v1.x), f2bf(v1.y), f2bf(v1.z), f2bf(v1.w)};
            *(uint4*)(dst + c) = *(uint4*)u;
        }
    }
}

// ---------------- per-node attention scores ps/pd [NT,8] ----------------
__global__ __launch_bounds__(256) void k_scores(const float* __restrict__ z,
                                                const float* __restrict__ a_src,
                                                const float* __restrict__ a_dst,
                                                float* __restrict__ ps, float* __restrict__ pd) {
    int wave = threadIdx.x >> 6, l = threadIdx.x & 63;
    int n = blockIdx.x * 4 + wave;
    const float* zr = z + (size_t)n * HA;
    float s[NH], d[NH];
#pragma unroll
    for (int i = 0; i < NH; i++) {
        float zv = zr[i * 64 + l];
        s[i] = zv * a_src[i * 64 + l];
        d[i] = zv * a_dst[i * 64 + l];
    }
#pragma unroll
    for (int i = 0; i < NH; i++) {
#pragma unroll
        for (int off = 32; off > 0; off >>= 1) {
            s[i] += __shfl_xor(s[i], off);
            d[i] += __shfl_xor(d[i], off);
        }
    }
    if (l == 0) {
#pragma unroll
        for (int i = 0; i < NH; i++) {
            ps[(size_t)n * NH + i] = s[i];
            pd[(size_t)n * NH + i] = d[i];
        }
    }
}

// ---------------- per-graph edge softmax -> alpha [E,8] ----------------
__global__ __launch_bounds__(256) void k_attn(const int* __restrict__ es, const int* __restrict__ ed,
                                              const float* __restrict__ ps, const float* __restrict__ pd,
                                              float* __restrict__ alpha) {
    __shared__ float sps[EPG], spd[EPG], esc[EPG * NH], sm[NPG * NH], sden[NPG * NH];
    __shared__ int sl[EPG], dl[EPG];
    int b = blockIdx.x, t = threadIdx.x;
    for (int i = t; i < EPG; i += 256) {
        sps[i] = ps[(size_t)b * EPG + i];
        spd[i] = pd[(size_t)b * EPG + i];
        sl[i] = es[b * EPG + i] - b * NPG;
        dl[i] = ed[b * EPG + i] - b * NPG;
    }
    __syncthreads();
    for (int i = t; i < EPG * NH; i += 256) {
        int e = i >> 3, h = i & 7;
        float sc = sps[sl[e] * NH + h] + spd[dl[e] * NH + h];
        esc[i] = sc > 0.f ? sc : 0.2f * sc;
    }
    __syncthreads();
    for (int i = t; i < NPG * NH; i += 256) {
        int n = i >> 3, h = i & 7;
        float m = -INFINITY;
        for (int e = 0; e < EPG; e++)
            if (dl[e] == n) m = fmaxf(m, esc[e * NH + h]);
        if (m == -INFINITY) m = 0.f;
        float den = 0.f;
        for (int e = 0; e < EPG; e++)
            if (dl[e] == n) den += expf(esc[e * NH + h] - m);
        sm[i] = m; sden[i] = den;
    }
    __syncthreads();
    for (int i = t; i < EPG * NH; i += 256) {
        int e = i >> 3, h = i & 7;
        float a = expf(esc[i] - sm[dl[e] * NH + h]) / (sden[dl[e] * NH + h] + 1e-9f);
        alpha[((size_t)b * EPG + e) * NH + h] = a;
    }
}

// ---------------- aggregation -> bf16 gnn [NT][512] ----------------
__global__ __launch_bounds__(256) void k_agg(const int* __restrict__ es, const int* __restrict__ ed,
                                             const float* __restrict__ alpha, const float* __restrict__ z,
                                             ushort* __restrict__ gnnB) {
    __shared__ float zt[NPG * AD];
    __shared__ float al[EPG];
    __shared__ int srcl[EPG], dll[EPG], order[EPG], cnt[NPG], bstart[NPG + 1];
    int b = blockIdx.x >> 3, h = blockIdx.x & 7;
    int t = threadIdx.x;
    for (int i = t; i < NPG * AD; i += 256)
        zt[i] = z[((size_t)b * NPG + (i >> 6)) * HA + (h << 6) + (i & 63)];
    for (int e = t; e < EPG; e += 256) {
        srcl[e] = es[b * EPG + e] - b * NPG;
        dll[e]  = ed[b * EPG + e] - b * NPG;
        al[e]   = alpha[((size_t)b * EPG + e) * NH + h];
    }
    if (t < NPG) cnt[t] = 0;
    __syncthreads();
    for (int e = t; e < EPG; e += 256) atomicAdd(&cnt[dll[e]], 1);
    __syncthreads();
    if (t == 0) {
        int s = 0;
        for (int n = 0; n < NPG; n++) { bstart[n] = s; s += cnt[n]; cnt[n] = bstart[n]; }
        bstart[NPG] = s;
        for (int e = 0; e < EPG; e++) order[cnt[dll[e]]++] = e;
    }
    __syncthreads();
    for (int i = t; i < NPG * AD; i += 256) {
        int n = i >> 6, d = i & 63;
        float acc = 0.f;
        for (int j = bstart[n]; j < bstart[n + 1]; j++) {
            int e = order[j];
            acc = fmaf(al[e], zt[srcl[e] * AD + d], acc);
        }
        gnnB[((size_t)b * NPG + n) * HA + (h << 6) + d] = f2bf(acc);
    }
}

extern "C" void kernel_launch(void* const* d_in, const int* in_sizes, int n_in,
                              void* d_out, int out_size, void* d_ws, size_t ws_size,
                              hipStream_t stream) {
    const float* locf  = (const float*)d_in[0];
    const float* gf    = (const float*)d_in[1];
    const int*   ei    = (const int*)d_in[2];
    const float* W1g   = (const float*)d_in[3];
    const float* b1g   = (const float*)d_in[4];
    const float* W2g   = (const float*)d_in[5];
    const float* b2g   = (const float*)d_in[6];
    const float* Wp    = (const float*)d_in[7];
    const float* bp    = (const float*)d_in[8];
    const float* Wg    = (const float*)d_in[9];
    const float* a_src = (const float*)d_in[10];
    const float* a_dst = (const float*)d_in[11];
    const float* Wllm  = (const float*)d_in[12];
    const float* bllm  = (const float*)d_in[13];
    float* out = (float*)d_out;
    float* ws  = (float*)d_ws;
    const int* es = ei;
    const int* ed = ei + NE;

    // d_out scratch layout (floats; all regions dead before GEMM5 rewrites d_out)
    float*  z      = out;                               // 8,912,896 f
    ushort* W1gT   = (ushort*)(out + 8912896);          // 50,331,648 bf16 (dead after GEMM1)
    ushort* hB     = (ushort*)(out + 8912896);          // 17,825,792 bf16 (overlaps W1gT, written GEMM3)
    ushort* poolB  = (ushort*)(out + 34078720);         // 12,582,912 bf16
    float*  part1  = out + 40370176;                    // 8,388,608 f
    ushort* g1B    = (ushort*)(out + 48758784);         // 1,048,576 bf16
    ushort* W2gT   = (ushort*)(out + 49283072);         // 2,359,296 bf16
    ushort* WpT    = (ushort*)(out + 50462720);         // 1,179,648 bf16
    ushort* WgT    = (ushort*)(out + 51052544);         // 524,288 bf16
    ushort* outgB  = (ushort*)(out + 51314688);         // 589,824 bf16
    ushort* nodesB = (ushort*)(out + 51609600);         // 20,054,016 bf16 (ends 61,636,608 f < 71,303,168)
    // d_ws layout (27.6 MB; GEMM5 inputs live here, never in d_out)
    ushort* WllmT = (ushort*)ws;                        // 2,097,152 bf16
    float*  ps    = ws + 1048576;                       // 139,264 f
    float*  pd    = ws + 1187840;                       // 139,264 f
    float*  alpha = ws + 1327104;                       // 1,114,112 f
    ushort* gnnB  = (ushort*)(ws + 2441216);            // 8,912,896 bf16 (ends 6,897,664 f)

    // weight transposes -> bf16 [N][K]
    k_transpose<<<dim3(64, 768), 256, 0, stream>>>(W1g, W1gT, C32, GPD);
    k_transpose<<<dim3(36, 64), 256, 0, stream>>>(W2g, W2gT, GPD, FEAT);
    k_transpose<<<dim3(32, 36), 256, 0, stream>>>(Wp, WpT, FEAT, HID);
    k_transpose<<<dim3(16, 32), 256, 0, stream>>>(Wg, WgT, HID, HA);
    k_transpose<<<dim3(128, 16), 256, 0, stream>>>(Wllm, WllmT, HA, LLM);
    // pool -> bf16
    k_pool<<<24576, 256, 0, stream>>>(gf, poolB);
    // GEMM1 split-K=8: [512,24576]x[24576,2048] -> f32 partials
    k_gemm_bf<true, false, false, false><<<dim3(16, 4, 8), 256, 0, stream>>>(
        poolB, W1gT, nullptr, part1, 512, GPD, C32, 3072);
    // reduce + b1g + relu -> bf16 g1
    k_red1<<<4096, 256, 0, stream>>>(part1, b1g, g1B);
    // GEMM2: [512,2048]x[2048,1152] + b2g -> bf16 outg
    k_gemm_bf<false, true, false, true><<<dim3(9, 4, 1), 256, 0, stream>>>(
        g1B, W2gT, b2g, outgB, 512, FEAT, GPD, 0);
    // build node matrix
    k_nodes<<<NT, 256, 0, stream>>>(outgB, locf, nodesB);
    // GEMM3: relu(nodes x Wp + bp) -> bf16 h [17408,1024]
    k_gemm_bf<false, true, true, true><<<dim3(8, 136, 1), 256, 0, stream>>>(
        nodesB, WpT, bp, hB, NT, HID, FEAT, 0);
    // GEMM4: z = h x Wg -> f32 [17408,512]
    k_gemm_bf<false, false, false, false><<<dim3(4, 136, 1), 256, 0, stream>>>(
        hB, WgT, nullptr, z, NT, HA, HID, 0);
    // graph attention
    k_scores<<<4352, 256, 0, stream>>>(z, a_src, a_dst, ps, pd);
    k_attn<<<BB, 256, 0, stream>>>(es, ed, ps, pd, alpha);
    k_agg<<<BB * NH, 256, 0, stream>>>(es, ed, alpha, z, gnnB);
    // GEMM5: out = gnn x Wllm + bllm -> f32 [17408,4096]
    k_gemm_bf<false, true, false, false><<<dim3(32, 136, 1), 256, 0, stream>>>(
        gnnB, WllmT, bllm, out, NT, LLM, HA, 0);
}

// Round 4
// 682.669 us; speedup vs baseline: 3.9461x; 1.0911x over previous
//
#include <hip/hip_runtime.h>
#include <hip/hip_bf16.h>
#include <math.h>

#define BB    512
#define NPG   34
#define NT    17408
#define FEAT  1152
#define GPD   2048
#define HID   1024
#define NH    8
#define AD    64
#define HA    512
#define LLM   4096
#define EPG   272
#define NE    139264
#define C32   24576
#define CC    768

#define AS3 __attribute__((address_space(3)))
#define AS1 __attribute__((address_space(1)))

typedef __attribute__((ext_vector_type(8))) short short8v;
typedef __attribute__((ext_vector_type(4))) float f32x4;

__device__ __forceinline__ ushort f2bf(float f) {
    __hip_bfloat16 h = __float2bfloat16(f);
    return __builtin_bit_cast(ushort, h);
}

// ---------------- transpose + fp32->bf16: W[R][Cn] -> WT[Cn][R] ----------------
__global__ __launch_bounds__(256) void k_transpose(const float* __restrict__ W,
                                                   ushort* __restrict__ WT, int R, int Cn) {
    __shared__ float tile[32][33];
    int c0 = blockIdx.x * 32, r0 = blockIdx.y * 32;
    int tc = threadIdx.x & 31, tr = threadIdx.x >> 5;
#pragma unroll
    for (int i = 0; i < 4; i++)
        tile[tr + i * 8][tc] = W[(size_t)(r0 + tr + i * 8) * Cn + c0 + tc];
    __syncthreads();
#pragma unroll
    for (int it = 0; it < 2; it++) {
        int p = threadIdx.x + it * 256;
        int c = p >> 4, pr = (p & 15) << 1;
        ushort2 v;
        v.x = f2bf(tile[pr][c]);
        v.y = f2bf(tile[pr + 1][c]);
        *(ushort2*)&WT[(size_t)(c0 + c) * R + r0 + pr] = v;
    }
}

// ---------------- pool: [B,768,8,8,4] -> bf16 [B,24576] (2x2x2 mean) ----------------
__global__ __launch_bounds__(256) void k_pool(const float* __restrict__ gf, ushort* __restrict__ outB) {
    int t = blockIdx.x * 256 + threadIdx.x;
    int q = t & 15; int bc = t >> 4;
    int dO = q >> 2, hO = q & 3;
    const float* p = gf + (size_t)bc * 256 + dO * 64 + hO * 8;
    float4 r00 = *(const float4*)(p);
    float4 r01 = *(const float4*)(p + 4);
    float4 r10 = *(const float4*)(p + 32);
    float4 r11 = *(const float4*)(p + 36);
    float o0 = (r00.x + r00.y + r01.x + r01.y + r10.x + r10.y + r11.x + r11.y) * 0.125f;
    float o1 = (r00.z + r00.w + r01.z + r01.w + r10.z + r10.w + r11.z + r11.w) * 0.125f;
    int b = bc / CC, c = bc % CC;
    ushort2 v; v.x = f2bf(o0); v.y = f2bf(o1);
    *(ushort2*)(outB + (size_t)b * C32 + c * 32 + dO * 8 + hO * 2) = v;
}

// ================= 256x256 8-phase bf16 MFMA GEMM (T2+T3+T4+T5) =================
// Race-fixed schedule: per-tile stage order B0,B1,A0,A1, each strictly after the
// last ds_read of that region; counted vmcnt(4) at phases 4/8 (ledger-derived).
#define GLDS(gp, lp) __builtin_amdgcn_global_load_lds((const AS1 void*)(gp), (AS3 void*)(lp), 16, 0, 0)
#define STAGE_A(buf, h, tt) { \
    const ushort* s_ = gAs + (size_t)(tt) * 64 + (size_t)(2 * (h)) * rK; \
    ushort* d_ = lds + (buf) * 32768 + (2 * (h)) * 4096 + (w << 9); \
    GLDS(s_, d_); GLDS(s_ + rK, d_ + 4096); }
#define STAGE_B(buf, h, tt) { \
    const ushort* s_ = gBs + (size_t)(tt) * 64 + (size_t)(2 * (h)) * rK; \
    ushort* d_ = lds + (buf) * 32768 + 16384 + (2 * (h)) * 4096 + (w << 9); \
    GLDS(s_, d_); GLDS(s_ + rK, d_ + 4096); }
#define DSRA(BO, mh) { _Pragma("unroll") for (int mf = 0; mf < 4; mf++) { \
    const ushort* p_ = lds + (BO) + aBase + ((mh) * 64 + mf * 16) * 64; \
    aF[mf][0] = *(const short8v*)(p_ + k0s); \
    aF[mf][1] = *(const short8v*)(p_ + k1s); } }
#define DSRB(BO, nh, BF) { _Pragma("unroll") for (int nf = 0; nf < 2; nf++) { \
    const ushort* p_ = lds + (BO) + bBase + ((nh) * 32 + nf * 16) * 64; \
    BF[nf][0] = *(const short8v*)(p_ + k0s); \
    BF[nf][1] = *(const short8v*)(p_ + k1s); } }
#define MM(mh, nh, BF) { \
    asm volatile("s_waitcnt lgkmcnt(0)" ::: "memory"); \
    __builtin_amdgcn_sched_barrier(0); \
    __builtin_amdgcn_s_setprio(1); \
    _Pragma("unroll") for (int mf = 0; mf < 4; mf++) \
    _Pragma("unroll") for (int nf = 0; nf < 2; nf++) { \
        acc[(mh)*4+mf][(nh)*2+nf] = __builtin_amdgcn_mfma_f32_16x16x32_bf16(aF[mf][0], BF[nf][0], acc[(mh)*4+mf][(nh)*2+nf], 0, 0, 0); \
        acc[(mh)*4+mf][(nh)*2+nf] = __builtin_amdgcn_mfma_f32_16x16x32_bf16(aF[mf][1], BF[nf][1], acc[(mh)*4+mf][(nh)*2+nf], 0, 0, 0); } \
    __builtin_amdgcn_s_setprio(0); }
#define BAR __builtin_amdgcn_s_barrier()
#define VMW4 { asm volatile("s_waitcnt vmcnt(4)" ::: "memory"); __builtin_amdgcn_sched_barrier(0); }

template<bool SPLITK, bool BIAS, bool RELU, bool OUTBF>
__global__ __launch_bounds__(512, 2) void k_gemm256(
    const ushort* __restrict__ A, const ushort* __restrict__ BT,
    const float* __restrict__ bias, void* __restrict__ Cout,
    int M, int N, int K, int kChunk) {
    __shared__ ushort lds[65536];            // 128 KiB: [buf][A 32KB | B 32KB]
    const int t = threadIdx.x;
    const int w = t >> 6, l = t & 63;
    const int wm = w >> 2, wn = w & 3;
    const int m0 = blockIdx.y * 256, n0 = blockIdx.x * 256;
    const int kBase = SPLITK ? blockIdx.z * kChunk : 0;
    const int NTt = (SPLITK ? kChunk : K) / 64;

    // staging source: linear LDS dest; inverse swizzle folded into global k-offset
    // swizzle: ushort-col ^= ((row>>2)&1)<<5 | ((row>>3)&1)<<4  (both-sides involution)
    const int rowLo = t >> 3;
    const int keSrc = ((t & 7) << 3) ^ (((rowLo >> 2) & 1) << 5) ^ (((rowLo >> 3) & 1) << 4);
    const ushort* gAs = A + (size_t)(m0 + rowLo) * K + kBase + keSrc;
    const ushort* gBs = BT + (size_t)(n0 + rowLo) * K + kBase + keSrc;
    const size_t rK = (size_t)64 * K;

    // fragment read geometry (swizzled ds_read addresses); row bits 2,3 == fcol bits 2,3
    const int fcol = l & 15, fk = (l >> 4) << 3;
    const int flipR = (((l >> 2) & 1) << 5) | (((l >> 3) & 1) << 4);
    const int k0s = fk ^ flipR;
    const int k1s = fk ^ 32 ^ flipR;
    const int aBase = (wm * 128 + fcol) * 64;
    const int bBase = 16384 + (wn * 64 + fcol) * 64;

    short8v aF[4][2], bF0[2][2], bF1[2][2];
    f32x4 acc[8][4] = {};

    // prologue: tile0 {B0,B1,A0,A1} + tile1 {B0,B1}; confirm tile0 (retire 8, keep 4)
    STAGE_B(0, 0, 0); STAGE_B(0, 1, 0); STAGE_A(0, 0, 0); STAGE_A(0, 1, 0);
    STAGE_B(1, 0, 1); STAGE_B(1, 1, 1);
    VMW4;
    BAR;

    const int NITER = NTt >> 1;
    for (int it = 0; it < NITER; ++it) {
        const int t1 = 2 * it + 1;
        const int t2r = 2 * it + 2, t3r = 2 * it + 3;
        const int t2 = t2r < NTt ? t2r : 0;   // clamped dummies keep vmcnt uniform
        const int t3 = t3r < NTt ? t3r : 0;
        // ph1: read buf0 A-mh0 + B-nh0 (t0); stage buf1 A-half0 (t1; buf1-A free since prev ph7)
        DSRA(0, 0); DSRB(0, 0, bF0); STAGE_A(1, 0, t1);
        BAR; MM(0, 0, bF0); BAR;
        // ph2: read buf0 B-nh1 (last buf0-B read); stage buf1 A-half1
        DSRB(0, 1, bF1); STAGE_A(1, 1, t1);
        BAR; MM(0, 1, bF1); BAR;
        // ph3: read buf0 A-mh1 (last buf0-A read); stage buf0 B-half0 (t2; B free after ph2)
        DSRA(0, 1); STAGE_B(0, 0, t2);
        BAR; MM(1, 1, bF1); BAR;
        // ph4: stage buf0 B-half1; confirm buf1=t1 complete (retire t1's 4 half-tiles)
        STAGE_B(0, 1, t2); VMW4;
        BAR; MM(1, 0, bF0); BAR;
        // ph5: read buf1 A-mh0 + B-nh0 (t1); stage buf0 A-half0 (A free after ph3)
        DSRA(32768, 0); DSRB(32768, 0, bF0); STAGE_A(0, 0, t2);
        BAR; MM(0, 0, bF0); BAR;
        // ph6: read buf1 B-nh1 (last buf1-B read); stage buf0 A-half1
        DSRB(32768, 1, bF1); STAGE_A(0, 1, t2);
        BAR; MM(0, 1, bF1); BAR;
        // ph7: read buf1 A-mh1 (last buf1-A read); stage buf1 B-half0 (t3; free after ph6)
        DSRA(32768, 1); STAGE_B(1, 0, t3);
        BAR; MM(1, 1, bF1); BAR;
        // ph8: stage buf1 B-half1; confirm buf0=t2 complete for next ph1
        STAGE_B(1, 1, t3); VMW4;
        BAR; MM(1, 0, bF0); BAR;
    }
    asm volatile("s_waitcnt vmcnt(0)" ::: "memory");

    const int orow = (l >> 4) << 2;
#pragma unroll
    for (int mf = 0; mf < 8; mf++) {
#pragma unroll
        for (int nf = 0; nf < 4; nf++) {
            int col = n0 + wn * 64 + nf * 16 + fcol;
            float bv = BIAS ? bias[col] : 0.f;
#pragma unroll
            for (int r = 0; r < 4; r++) {
                int row = m0 + wm * 128 + mf * 16 + orow + r;
                float v = acc[mf][nf][r] + bv;
                if (RELU) v = v > 0.f ? v : 0.f;
                if (OUTBF) {
                    ((ushort*)Cout)[(size_t)row * N + col] = f2bf(v);
                } else {
                    size_t off = (size_t)row * N + col;
                    if (SPLITK) off += (size_t)blockIdx.z * (size_t)M * N;
                    ((float*)Cout)[off] = v;
                }
            }
        }
    }
}

// ---------------- 128x128 m97-style bf16 GEMM (kept for GEMM2, N=1152) ----------------
template<bool SPLITK, bool BIAS, bool RELU, bool OUTBF>
__global__ __launch_bounds__(256) void k_gemm_bf(
    const ushort* __restrict__ A, const ushort* __restrict__ BT,
    const float* __restrict__ bias, void* __restrict__ Cout,
    int M, int N, int K, int kChunk) {
    __shared__ ushort lA[128 * 32];
    __shared__ ushort lB[128 * 32];
    const int t = threadIdx.x;
    const int w = t >> 6, l = t & 63;
    const int m0 = blockIdx.y * 128, n0 = blockIdx.x * 128;
    const int kLen = SPLITK ? kChunk : K;
    const int k0 = SPLITK ? blockIdx.z * kChunk : 0;
    const int srow = w * 16 + (l >> 2);
    const int skq = (l & 3) << 3;
    const ushort* gA = A + (size_t)(m0 + srow) * K + k0 + skq;
    const ushort* gB = BT + (size_t)(n0 + srow) * K + k0 + skq;
    ushort* lA0 = lA + w * 512;
    ushort* lB0 = lB + w * 512;
    const size_t str64 = (size_t)64 * K;
    const int wr = (w >> 1) << 6, wc = (w & 1) << 6;
    const int fcol = l & 15, fk = (l >> 4) << 3;

    f32x4 acc[4][4] = {};
    for (int kk = 0; kk < kLen; kk += 32) {
        __syncthreads();
        GLDS(gA + kk,         lA0);
        GLDS(gA + kk + str64, lA0 + 2048);
        GLDS(gB + kk,         lB0);
        GLDS(gB + kk + str64, lB0 + 2048);
        __syncthreads();
        short8v a[4], b[4];
#pragma unroll
        for (int f = 0; f < 4; f++) {
            a[f] = *(const short8v*)(lA + (wr + f * 16 + fcol) * 32 + fk);
            b[f] = *(const short8v*)(lB + (wc + f * 16 + fcol) * 32 + fk);
        }
#pragma unroll
        for (int i = 0; i < 4; i++)
#pragma unroll
            for (int j = 0; j < 4; j++)
                acc[i][j] = __builtin_amdgcn_mfma_f32_16x16x32_bf16(a[i], b[j], acc[i][j], 0, 0, 0);
    }
    const int orow = (l >> 4) << 2;
#pragma unroll
    for (int i = 0; i < 4; i++) {
#pragma unroll
        for (int j = 0; j < 4; j++) {
            int col = n0 + wc + j * 16 + fcol;
            float bv = BIAS ? bias[col] : 0.f;
#pragma unroll
            for (int r = 0; r < 4; r++) {
                int row = m0 + wr + i * 16 + orow + r;
                float v = acc[i][j][r] + bv;
                if (RELU) v = v > 0.f ? v : 0.f;
                if (OUTBF) {
                    ((ushort*)Cout)[(size_t)row * N + col] = f2bf(v);
                } else {
                    size_t off = (size_t)row * N + col;
                    if (SPLITK) off += (size_t)blockIdx.z * (size_t)M * N;
                    ((float*)Cout)[off] = v;
                }
            }
        }
    }
}

// ---------------- reduce split-K partials + bias (+relu) -> bf16 ----------------
template<int NP, bool RELU>
__global__ __launch_bounds__(256) void k_red(const float* __restrict__ part,
                                             const float* __restrict__ bias,
                                             ushort* __restrict__ outB,
                                             int N, int stride) {
    int i = blockIdx.x * 256 + threadIdx.x;
    float s = bias[i % N];
#pragma unroll
    for (int q = 0; q < NP; q++) s += part[i + (size_t)q * stride];
    if (RELU) s = s > 0.f ? s : 0.f;
    outB[i] = f2bf(s);
}

// ---------------- build bf16 node matrix [NT][FEAT] ----------------
__global__ __launch_bounds__(256) void k_nodes(const ushort* __restrict__ outgB,
                                               const float* __restrict__ locf,
                                               ushort* __restrict__ nodesB) {
    int node = blockIdx.x;
    int b = node / NPG, j = node % NPG;
    ushort* dst = nodesB + (size_t)node * FEAT;
    if (threadIdx.x < 144) {
        int c = threadIdx.x * 8;
        if (j == 0) {
            *(uint4*)(dst + c) = *(const uint4*)(outgB + (size_t)b * FEAT + c);
        } else {
            const float* s = locf + ((size_t)b * 33 + (j - 1)) * FEAT + c;
            float4 v0 = *(const float4*)s, v1 = *(const float4*)(s + 4);
            ushort u[8] = {f2bf(v0.x), f2bf(v0.y), f2bf(v0.z), f2bf(v0.w),
                           f2bf(v1.x), f2bf(v1.y), f2bf(v1.z), f2bf(v1.w)};
            *(uint4*)(dst + c) = *(uint4*)u;
        }
    }
}

// ---------------- per-node attention scores ps/pd [NT,8] ----------------
__global__ __launch_bounds__(256) void k_scores(const float* __restrict__ z,
                                                const float* __restrict__ a_src,
                                                const float* __restrict__ a_dst,
                                                float* __restrict__ ps, float* __restrict__ pd) {
    int wave = threadIdx.x >> 6, l = threadIdx.x & 63;
    int n = blockIdx.x * 4 + wave;
    const float* zr = z + (size_t)n * HA;
    float s[NH], d[NH];
#pragma unroll
    for (int i = 0; i < NH; i++) {
        float zv = zr[i * 64 + l];
        s[i] = zv * a_src[i * 64 + l];
        d[i] = zv * a_dst[i * 64 + l];
    }
#pragma unroll
    for (int i = 0; i < NH; i++) {
#pragma unroll
        for (int off = 32; off > 0; off >>= 1) {
            s[i] += __shfl_xor(s[i], off);
            d[i] += __shfl_xor(d[i], off);
        }
    }
    if (l == 0) {
#pragma unroll
        for (int i = 0; i < NH; i++) {
            ps[(size_t)n * NH + i] = s[i];
            pd[(size_t)n * NH + i] = d[i];
        }
    }
}

// ---------------- per-graph edge softmax -> alpha [E,8] ----------------
__global__ __launch_bounds__(256) void k_attn(const int* __restrict__ es, const int* __restrict__ ed,
                                              const float* __restrict__ ps, const float* __restrict__ pd,
                                              float* __restrict__ alpha) {
    __shared__ float sps[EPG], spd[EPG], esc[EPG * NH], sm[NPG * NH], sden[NPG * NH];
    __shared__ int sl[EPG], dl[EPG];
    int b = blockIdx.x, t = threadIdx.x;
    for (int i = t; i < EPG; i += 256) {
        sps[i] = ps[(size_t)b * EPG + i];
        spd[i] = pd[(size_t)b * EPG + i];
        sl[i] = es[b * EPG + i] - b * NPG;
        dl[i] = ed[b * EPG + i] - b * NPG;
    }
    __syncthreads();
    for (int i = t; i < EPG * NH; i += 256) {
        int e = i >> 3, h = i & 7;
        float sc = sps[sl[e] * NH + h] + spd[dl[e] * NH + h];
        esc[i] = sc > 0.f ? sc : 0.2f * sc;
    }
    __syncthreads();
    for (int i = t; i < NPG * NH; i += 256) {
        int n = i >> 3, h = i & 7;
        float m = -INFINITY;
        for (int e = 0; e < EPG; e++)
            if (dl[e] == n) m = fmaxf(m, esc[e * NH + h]);
        if (m == -INFINITY) m = 0.f;
        float den = 0.f;
        for (int e = 0; e < EPG; e++)
            if (dl[e] == n) den += expf(esc[e * NH + h] - m);
        sm[i] = m; sden[i] = den;
    }
    __syncthreads();
    for (int i = t; i < EPG * NH; i += 256) {
        int e = i >> 3, h = i & 7;
        float a = expf(esc[i] - sm[dl[e] * NH + h]) / (sden[dl[e] * NH + h] + 1e-9f);
        alpha[((size_t)b * EPG + e) * NH + h] = a;
    }
}

// ---------------- aggregation -> bf16 gnn [NT][512] ----------------
__global__ __launch_bounds__(256) void k_agg(const int* __restrict__ es, const int* __restrict__ ed,
                                             const float* __restrict__ alpha, const float* __restrict__ z,
                                             ushort* __restrict__ gnnB) {
    __shared__ float zt[NPG * AD];
    __shared__ float al[EPG];
    __shared__ int srcl[EPG], dll[EPG], order[EPG], cnt[NPG], bstart[NPG + 1];
    int b = blockIdx.x >> 3, h = blockIdx.x & 7;
    int t = threadIdx.x;
    for (int i = t; i < NPG * AD; i += 256)
        zt[i] = z[((size_t)b * NPG + (i >> 6)) * HA + (h << 6) + (i & 63)];
    for (int e = t; e < EPG; e += 256) {
        srcl[e] = es[b * EPG + e] - b * NPG;
        dll[e]  = ed[b * EPG + e] - b * NPG;
        al[e]   = alpha[((size_t)b * EPG + e) * NH + h];
    }
    if (t < NPG) cnt[t] = 0;
    __syncthreads();
    for (int e = t; e < EPG; e += 256) atomicAdd(&cnt[dll[e]], 1);
    __syncthreads();
    if (t == 0) {
        int s = 0;
        for (int n = 0; n < NPG; n++) { bstart[n] = s; s += cnt[n]; cnt[n] = bstart[n]; }
        bstart[NPG] = s;
        for (int e = 0; e < EPG; e++) order[cnt[dll[e]]++] = e;
    }
    __syncthreads();
    for (int i = t; i < NPG * AD; i += 256) {
        int n = i >> 6, d = i & 63;
        float acc = 0.f;
        for (int j = bstart[n]; j < bstart[n + 1]; j++) {
            int e = order[j];
            acc = fmaf(al[e], zt[srcl[e] * AD + d], acc);
        }
        gnnB[((size_t)b * NPG + n) * HA + (h << 6) + d] = f2bf(acc);
    }
}

extern "C" void kernel_launch(void* const* d_in, const int* in_sizes, int n_in,
                              void* d_out, int out_size, void* d_ws, size_t ws_size,
                              hipStream_t stream) {
    const float* locf  = (const float*)d_in[0];
    const float* gf    = (const float*)d_in[1];
    const int*   ei    = (const int*)d_in[2];
    const float* W1g   = (const float*)d_in[3];
    const float* b1g   = (const float*)d_in[4];
    const float* W2g   = (const float*)d_in[5];
    const float* b2g   = (const float*)d_in[6];
    const float* Wp    = (const float*)d_in[7];
    const float* bp    = (const float*)d_in[8];
    const float* Wg    = (const float*)d_in[9];
    const float* a_src = (const float*)d_in[10];
    const float* a_dst = (const float*)d_in[11];
    const float* Wllm  = (const float*)d_in[12];
    const float* bllm  = (const float*)d_in[13];
    float* out = (float*)d_out;
    float* ws  = (float*)d_ws;
    const int* es = ei;
    const int* ed = ei + NE;

    // d_out scratch layout (float offsets; every region dead before GEMM5 overwrite)
    float*  z      = out;                               // [0, 8,912,896)
    ushort* W1gT   = (ushort*)(out + 8912896);          // 25,165,824 f (dead after GEMM1)
    ushort* hB     = (ushort*)(out + 8912896);          // 8,912,896 f (overlaps W1gT)
    ushort* poolB  = (ushort*)(out + 34078720);         // 6,291,456 f
    float*  part1  = out + 40370176;                    // 12,582,912 f (12 x 512x2048)
    ushort* g1B    = (ushort*)(out + 52953088);         // 524,288 f
    ushort* W2gT   = (ushort*)(out + 53477376);         // 1,179,648 f
    ushort* WpT    = (ushort*)(out + 54657024);         // 589,824 f
    ushort* WgT    = (ushort*)(out + 55246848);         // 262,144 f
    ushort* outgB  = (ushort*)(out + 55508992);         // 294,912 f
    float*  part2  = out + 55803904;                    // 2,359,296 f (4 x 512x1152)
    ushort* nodesB = (ushort*)(out + 58163200);         // 10,027,008 f (ends 68,190,208 < 71,303,168)
    // d_ws layout (27.6 MB; GEMM5 inputs live here, never in d_out)
    ushort* WllmT = (ushort*)ws;                        // 1,048,576 f
    float*  ps    = ws + 1048576;
    float*  pd    = ws + 1187840;
    float*  alpha = ws + 1327104;
    ushort* gnnB  = (ushort*)(ws + 2441216);            // 4,456,448 f

    // weight transposes -> bf16 [N][K]
    k_transpose<<<dim3(64, 768), 256, 0, stream>>>(W1g, W1gT, C32, GPD);
    k_transpose<<<dim3(36, 64), 256, 0, stream>>>(W2g, W2gT, GPD, FEAT);
    k_transpose<<<dim3(32, 36), 256, 0, stream>>>(Wp, WpT, FEAT, HID);
    k_transpose<<<dim3(16, 32), 256, 0, stream>>>(Wg, WgT, HID, HA);
    k_transpose<<<dim3(128, 16), 256, 0, stream>>>(Wllm, WllmT, HA, LLM);
    // pool -> bf16
    k_pool<<<24576, 256, 0, stream>>>(gf, poolB);
    // GEMM1 (256sq 8-phase, split-K=12): [512,24576]x[24576,2048] -> f32 partials
    k_gemm256<true, false, false, false><<<dim3(8, 2, 12), 512, 0, stream>>>(
        poolB, W1gT, nullptr, part1, 512, GPD, C32, 2048);
    k_red<12, true><<<4096, 256, 0, stream>>>(part1, b1g, g1B, GPD, 1048576);
    // GEMM2 (128sq, split-K=4): [512,2048]x[2048,1152] -> partials; reduce + b2g
    k_gemm_bf<true, false, false, false><<<dim3(9, 4, 4), 256, 0, stream>>>(
        g1B, W2gT, nullptr, part2, 512, FEAT, GPD, 512);
    k_red<4, false><<<2304, 256, 0, stream>>>(part2, b2g, outgB, FEAT, 589824);
    // build node matrix
    k_nodes<<<NT, 256, 0, stream>>>(outgB, locf, nodesB);
    // GEMM3 (256sq): relu(nodes x Wp + bp) -> bf16 h [17408,1024]
    k_gemm256<false, true, true, true><<<dim3(4, 68), 512, 0, stream>>>(
        nodesB, WpT, bp, hB, NT, HID, FEAT, 0);
    // GEMM4 (256sq): z = h x Wg -> f32 [17408,512]
    k_gemm256<false, false, false, false><<<dim3(2, 68), 512, 0, stream>>>(
        hB, WgT, nullptr, z, NT, HA, HID, 0);
    // graph attention
    k_scores<<<4352, 256, 0, stream>>>(z, a_src, a_dst, ps, pd);
    k_attn<<<BB, 256, 0, stream>>>(es, ed, ps, pd, alpha);
    k_agg<<<BB * NH, 256, 0, stream>>>(es, ed, alpha, z, gnnB);
    // GEMM5 (256sq): out = gnn x Wllm + bllm -> f32 [17408,4096]
    k_gemm256<false, true, false, false><<<dim3(16, 68), 512, 0, stream>>>(
        gnnB, WllmT, bllm, out, NT, LLM, HA, 0);
}

// Round 5
// 595.227 us; speedup vs baseline: 4.5258x; 1.1469x over previous
//
#include <hip/hip_runtime.h>
#include <hip/hip_bf16.h>
#include <math.h>

#define BB    512
#define NPG   34
#define NT    17408
#define FEAT  1152
#define GPD   2048
#define HID   1024
#define NH    8
#define AD    64
#define HA    512
#define LLM   4096
#define EPG   272
#define NE    139264
#define C32   24576
#define CC    768

#define AS3 __attribute__((address_space(3)))
#define AS1 __attribute__((address_space(1)))

typedef __attribute__((ext_vector_type(8))) short short8v;
typedef __attribute__((ext_vector_type(4))) float f32x4;

__device__ __forceinline__ ushort f2bf(float f) {
    __hip_bfloat16 h = __float2bfloat16(f);
    return __builtin_bit_cast(ushort, h);
}

// ---------------- transpose body: W[R][Cn] -> bf16 WT[Cn][R] ----------------
__device__ __forceinline__ void d_transpose(const float* __restrict__ W, ushort* __restrict__ WT,
                                            int R, int Cn, int bx, int by,
                                            float (*tile)[33], int tid) {
    int c0 = bx * 32, r0 = by * 32;
    int tc = tid & 31, tr = tid >> 5;
#pragma unroll
    for (int i = 0; i < 4; i++)
        tile[tr + i * 8][tc] = W[(size_t)(r0 + tr + i * 8) * Cn + c0 + tc];
    __syncthreads();
#pragma unroll
    for (int it = 0; it < 2; it++) {
        int p = tid + it * 256;
        int c = p >> 4, pr = (p & 15) << 1;
        ushort2 v;
        v.x = f2bf(tile[pr][c]);
        v.y = f2bf(tile[pr + 1][c]);
        *(ushort2*)&WT[(size_t)(c0 + c) * R + r0 + pr] = v;
    }
}

// ---------------- pool body: [B,768,8,8,4] -> bf16 [B,24576] (2x2x2 mean) ----------------
__device__ __forceinline__ void d_pool(const float* __restrict__ gf, ushort* __restrict__ outB,
                                       int blk, int tid) {
    int t = blk * 256 + tid;
    int q = t & 15; int bc = t >> 4;
    int dO = q >> 2, hO = q & 3;
    const float* p = gf + (size_t)bc * 256 + dO * 64 + hO * 8;
    float4 r00 = *(const float4*)(p);
    float4 r01 = *(const float4*)(p + 4);
    float4 r10 = *(const float4*)(p + 32);
    float4 r11 = *(const float4*)(p + 36);
    float o0 = (r00.x + r00.y + r01.x + r01.y + r10.x + r10.y + r11.x + r11.y) * 0.125f;
    float o1 = (r00.z + r00.w + r01.z + r01.w + r10.z + r10.w + r11.z + r11.w) * 0.125f;
    int b = bc / CC, c = bc % CC;
    ushort2 v; v.x = f2bf(o0); v.y = f2bf(o1);
    *(ushort2*)(outB + (size_t)b * C32 + c * 32 + dO * 8 + hO * 2) = v;
}

// ---------------- fused prep: 5 weight transposes + pool, one launch ----------------
// block ranges: [0,49152) W1g | [49152,51456) W2g | [51456,52608) Wp |
//               [52608,53120) Wg | [53120,55168) Wllm | [55168,79744) pool
__global__ __launch_bounds__(256) void k_prep(
    const float* __restrict__ W1g, ushort* __restrict__ W1gT,
    const float* __restrict__ W2g, ushort* __restrict__ W2gT,
    const float* __restrict__ Wp,  ushort* __restrict__ WpT,
    const float* __restrict__ Wg,  ushort* __restrict__ WgT,
    const float* __restrict__ Wllm, ushort* __restrict__ WllmT,
    const float* __restrict__ gf,  ushort* __restrict__ poolB) {
    __shared__ float tile[32][33];
    int blk = blockIdx.x, tid = threadIdx.x;
    if (blk < 49152) {
        d_transpose(W1g, W1gT, C32, GPD, blk & 63, blk >> 6, tile, tid);
    } else if (blk < 51456) {
        int l = blk - 49152; d_transpose(W2g, W2gT, GPD, FEAT, l % 36, l / 36, tile, tid);
    } else if (blk < 52608) {
        int l = blk - 51456; d_transpose(Wp, WpT, FEAT, HID, l & 31, l >> 5, tile, tid);
    } else if (blk < 53120) {
        int l = blk - 52608; d_transpose(Wg, WgT, HID, HA, l & 15, l >> 4, tile, tid);
    } else if (blk < 55168) {
        int l = blk - 53120; d_transpose(Wllm, WllmT, HA, LLM, l & 127, l >> 7, tile, tid);
    } else {
        d_pool(gf, poolB, blk - 55168, tid);
    }
}

// ================= 256x256 8-phase bf16 MFMA GEMM (T2+T3+T4+T5) =================
// K-loop schedule identical to the round-4 verified template (stage order B0,B1,A0,A1;
// counted vmcnt(4) at ph4/ph8). New: bijective XCD swizzle + LDS-staged epilogue.
#define GLDS(gp, lp) __builtin_amdgcn_global_load_lds((const AS1 void*)(gp), (AS3 void*)(lp), 16, 0, 0)
#define STAGE_A(buf, h, tt) { \
    const ushort* s_ = gAs + (size_t)(tt) * 64 + (size_t)(2 * (h)) * rK; \
    ushort* d_ = lds + (buf) * 32768 + (2 * (h)) * 4096 + (w << 9); \
    GLDS(s_, d_); GLDS(s_ + rK, d_ + 4096); }
#define STAGE_B(buf, h, tt) { \
    const ushort* s_ = gBs + (size_t)(tt) * 64 + (size_t)(2 * (h)) * rK; \
    ushort* d_ = lds + (buf) * 32768 + 16384 + (2 * (h)) * 4096 + (w << 9); \
    GLDS(s_, d_); GLDS(s_ + rK, d_ + 4096); }
#define DSRA(BO, mh) { _Pragma("unroll") for (int mf = 0; mf < 4; mf++) { \
    const ushort* p_ = lds + (BO) + aBase + ((mh) * 64 + mf * 16) * 64; \
    aF[mf][0] = *(const short8v*)(p_ + k0s); \
    aF[mf][1] = *(const short8v*)(p_ + k1s); } }
#define DSRB(BO, nh, BF) { _Pragma("unroll") for (int nf = 0; nf < 2; nf++) { \
    const ushort* p_ = lds + (BO) + bBase + ((nh) * 32 + nf * 16) * 64; \
    BF[nf][0] = *(const short8v*)(p_ + k0s); \
    BF[nf][1] = *(const short8v*)(p_ + k1s); } }
#define MM(mh, nh, BF) { \
    asm volatile("s_waitcnt lgkmcnt(0)" ::: "memory"); \
    __builtin_amdgcn_sched_barrier(0); \
    __builtin_amdgcn_s_setprio(1); \
    _Pragma("unroll") for (int mf = 0; mf < 4; mf++) \
    _Pragma("unroll") for (int nf = 0; nf < 2; nf++) { \
        acc[(mh)*4+mf][(nh)*2+nf] = __builtin_amdgcn_mfma_f32_16x16x32_bf16(aF[mf][0], BF[nf][0], acc[(mh)*4+mf][(nh)*2+nf], 0, 0, 0); \
        acc[(mh)*4+mf][(nh)*2+nf] = __builtin_amdgcn_mfma_f32_16x16x32_bf16(aF[mf][1], BF[nf][1], acc[(mh)*4+mf][(nh)*2+nf], 0, 0, 0); } \
    __builtin_amdgcn_s_setprio(0); }
#define BAR __builtin_amdgcn_s_barrier()
#define VMW4 { asm volatile("s_waitcnt vmcnt(4)" ::: "memory"); __builtin_amdgcn_sched_barrier(0); }

template<bool SPLITK, bool BIAS, bool RELU, bool OUTBF>
__global__ __launch_bounds__(512, 2) void k_gemm256(
    const ushort* __restrict__ A, const ushort* __restrict__ BT,
    const float* __restrict__ bias, void* __restrict__ Cout,
    int M, int N, int K, int kChunk) {
    __shared__ ushort lds[65536];            // 128 KiB: [buf][A 32KB | B 32KB]
    const int t = threadIdx.x;
    const int w = t >> 6, l = t & 63;
    const int wm = w >> 2, wn = w & 3;
    // bijective XCD swizzle over flattened (y,x); z (split-K) untouched
    const int gx = gridDim.x;
    const int nwg = gx * gridDim.y;
    const int id = blockIdx.y * gx + blockIdx.x;
    const int qx = nwg >> 3, rx = nwg & 7;
    const int xcd = id & 7, pos = id >> 3;
    const int nid = (xcd < rx ? xcd * (qx + 1) : rx * (qx + 1) + (xcd - rx) * qx) + pos;
    const int m0 = (nid / gx) * 256, n0 = (nid % gx) * 256;
    const int kBase = SPLITK ? blockIdx.z * kChunk : 0;
    const int NTt = (SPLITK ? kChunk : K) / 64;

    // staging source: linear LDS dest; inverse swizzle folded into global k-offset
    const int rowLo = t >> 3;
    const int keSrc = ((t & 7) << 3) ^ (((rowLo >> 2) & 1) << 5) ^ (((rowLo >> 3) & 1) << 4);
    const ushort* gAs = A + (size_t)(m0 + rowLo) * K + kBase + keSrc;
    const ushort* gBs = BT + (size_t)(n0 + rowLo) * K + kBase + keSrc;
    const size_t rK = (size_t)64 * K;

    // fragment read geometry (swizzled ds_read addresses)
    const int fcol = l & 15, fk = (l >> 4) << 3;
    const int flipR = (((l >> 2) & 1) << 5) | (((l >> 3) & 1) << 4);
    const int k0s = fk ^ flipR;
    const int k1s = fk ^ 32 ^ flipR;
    const int aBase = (wm * 128 + fcol) * 64;
    const int bBase = 16384 + (wn * 64 + fcol) * 64;

    short8v aF[4][2], bF0[2][2], bF1[2][2];
    f32x4 acc[8][4] = {};

    // prologue: tile0 {B0,B1,A0,A1} + tile1 {B0,B1}; confirm tile0
    STAGE_B(0, 0, 0); STAGE_B(0, 1, 0); STAGE_A(0, 0, 0); STAGE_A(0, 1, 0);
    STAGE_B(1, 0, 1); STAGE_B(1, 1, 1);
    VMW4;
    BAR;

    const int NITER = NTt >> 1;
    for (int it = 0; it < NITER; ++it) {
        const int t1 = 2 * it + 1;
        const int t2r = 2 * it + 2, t3r = 2 * it + 3;
        const int t2 = t2r < NTt ? t2r : 0;   // clamped dummies keep vmcnt uniform
        const int t3 = t3r < NTt ? t3r : 0;
        DSRA(0, 0); DSRB(0, 0, bF0); STAGE_A(1, 0, t1);
        BAR; MM(0, 0, bF0); BAR;
        DSRB(0, 1, bF1); STAGE_A(1, 1, t1);
        BAR; MM(0, 1, bF1); BAR;
        DSRA(0, 1); STAGE_B(0, 0, t2);
        BAR; MM(1, 1, bF1); BAR;
        STAGE_B(0, 1, t2); VMW4;
        BAR; MM(1, 0, bF0); BAR;
        DSRA(32768, 0); DSRB(32768, 0, bF0); STAGE_A(0, 0, t2);
        BAR; MM(0, 0, bF0); BAR;
        DSRB(32768, 1, bF1); STAGE_A(0, 1, t2);
        BAR; MM(0, 1, bF1); BAR;
        DSRA(32768, 1); STAGE_B(1, 0, t3);
        BAR; MM(1, 1, bF1); BAR;
        STAGE_B(1, 1, t3); VMW4;
        BAR; MM(1, 0, bF0); BAR;
    }
    asm volatile("s_waitcnt vmcnt(0)" ::: "memory");
    BAR;   // all waves drained their in-flight LDS writes before LDS reuse

    // ---- LDS-staged vectorized epilogue: 4 passes of 32 rows x 64 cols f32 ----
    const int orow = (l >> 4) << 2;
    float* eph = ((float*)lds) + w * 2176;   // wave-private 32x68 f32 (8.5 KB)
    const int ecol = (l & 15) << 2;
    const int erow4 = l >> 4;
#pragma unroll
    for (int pass = 0; pass < 4; pass++) {
#pragma unroll
        for (int mi = 0; mi < 2; mi++) {
            int mf = pass * 2 + mi;
#pragma unroll
            for (int nf = 0; nf < 4; nf++)
#pragma unroll
                for (int r = 0; r < 4; r++)
                    eph[(mi * 16 + orow + r) * 68 + nf * 16 + fcol] = acc[mf][nf][r];
        }
#pragma unroll
        for (int g = 0; g < 8; g++) {
            int lrow = g * 4 + erow4;
            f32x4 v = *(f32x4*)&eph[lrow * 68 + ecol];
            int row = m0 + wm * 128 + pass * 32 + lrow;
            int col = n0 + wn * 64 + ecol;
            if (BIAS) {
                float4 bb = *(const float4*)(bias + col);
                v[0] += bb.x; v[1] += bb.y; v[2] += bb.z; v[3] += bb.w;
            }
            if (RELU) {
#pragma unroll
                for (int q = 0; q < 4; q++) v[q] = v[q] > 0.f ? v[q] : 0.f;
            }
            if (OUTBF) {
                ushort4 u;
                u.x = f2bf(v[0]); u.y = f2bf(v[1]); u.z = f2bf(v[2]); u.w = f2bf(v[3]);
                *(ushort4*)&((ushort*)Cout)[(size_t)row * N + col] = u;
            } else {
                size_t off = (size_t)row * N + col;
                if (SPLITK) off += (size_t)blockIdx.z * (size_t)M * N;
                float4 fv = {v[0], v[1], v[2], v[3]};
                *(float4*)&((float*)Cout)[off] = fv;
            }
        }
        // next pass overwrites wave-private region; same-wave DS ordering handled by compiler
    }
}

// ---------------- 128x128 m97-style bf16 GEMM (kept for GEMM2, N=1152) ----------------
template<bool SPLITK, bool BIAS, bool RELU, bool OUTBF>
__global__ __launch_bounds__(256) void k_gemm_bf(
    const ushort* __restrict__ A, const ushort* __restrict__ BT,
    const float* __restrict__ bias, void* __restrict__ Cout,
    int M, int N, int K, int kChunk) {
    __shared__ ushort lA[128 * 32];
    __shared__ ushort lB[128 * 32];
    const int t = threadIdx.x;
    const int w = t >> 6, l = t & 63;
    const int m0 = blockIdx.y * 128, n0 = blockIdx.x * 128;
    const int kLen = SPLITK ? kChunk : K;
    const int k0 = SPLITK ? blockIdx.z * kChunk : 0;
    const int srow = w * 16 + (l >> 2);
    const int skq = (l & 3) << 3;
    const ushort* gA = A + (size_t)(m0 + srow) * K + k0 + skq;
    const ushort* gB = BT + (size_t)(n0 + srow) * K + k0 + skq;
    ushort* lA0 = lA + w * 512;
    ushort* lB0 = lB + w * 512;
    const size_t str64 = (size_t)64 * K;
    const int wr = (w >> 1) << 6, wc = (w & 1) << 6;
    const int fcol = l & 15, fk = (l >> 4) << 3;

    f32x4 acc[4][4] = {};
    for (int kk = 0; kk < kLen; kk += 32) {
        __syncthreads();
        GLDS(gA + kk,         lA0);
        GLDS(gA + kk + str64, lA0 + 2048);
        GLDS(gB + kk,         lB0);
        GLDS(gB + kk + str64, lB0 + 2048);
        __syncthreads();
        short8v a[4], b[4];
#pragma unroll
        for (int f = 0; f < 4; f++) {
            a[f] = *(const short8v*)(lA + (wr + f * 16 + fcol) * 32 + fk);
            b[f] = *(const short8v*)(lB + (wc + f * 16 + fcol) * 32 + fk);
        }
#pragma unroll
        for (int i = 0; i < 4; i++)
#pragma unroll
            for (int j = 0; j < 4; j++)
                acc[i][j] = __builtin_amdgcn_mfma_f32_16x16x32_bf16(a[i], b[j], acc[i][j], 0, 0, 0);
    }
    const int orow = (l >> 4) << 2;
#pragma unroll
    for (int i = 0; i < 4; i++) {
#pragma unroll
        for (int j = 0; j < 4; j++) {
            int col = n0 + wc + j * 16 + fcol;
            float bv = BIAS ? bias[col] : 0.f;
#pragma unroll
            for (int r = 0; r < 4; r++) {
                int row = m0 + wr + i * 16 + orow + r;
                float v = acc[i][j][r] + bv;
                if (RELU) v = v > 0.f ? v : 0.f;
                if (OUTBF) {
                    ((ushort*)Cout)[(size_t)row * N + col] = f2bf(v);
                } else {
                    size_t off = (size_t)row * N + col;
                    if (SPLITK) off += (size_t)blockIdx.z * (size_t)M * N;
                    ((float*)Cout)[off] = v;
                }
            }
        }
    }
}

// ---------------- reduce split-K partials + bias (+relu) -> bf16 ----------------
template<int NP, bool RELU>
__global__ __launch_bounds__(256) void k_red(const float* __restrict__ part,
                                             const float* __restrict__ bias,
                                             ushort* __restrict__ outB,
                                             int N, int stride) {
    int i = blockIdx.x * 256 + threadIdx.x;
    float s = bias[i % N];
#pragma unroll
    for (int q = 0; q < NP; q++) s += part[i + (size_t)q * stride];
    if (RELU) s = s > 0.f ? s : 0.f;
    outB[i] = f2bf(s);
}

// ---------------- build bf16 node matrix [NT][FEAT] (grid-strided, full blocks) ----------------
__global__ __launch_bounds__(256) void k_nodes(const ushort* __restrict__ outgB,
                                               const float* __restrict__ locf,
                                               ushort* __restrict__ nodesB) {
    int idx = blockIdx.x * 256 + threadIdx.x;   // over NT*144 = 2,506,752 16B-chunks
    int node = idx / 144, cc = idx - node * 144;
    int b = node / NPG, j = node - b * NPG;
    int c = cc * 8;
    ushort* dst = nodesB + (size_t)node * FEAT + c;
    if (j == 0) {
        *(uint4*)dst = *(const uint4*)(outgB + (size_t)b * FEAT + c);
    } else {
        const float* s = locf + ((size_t)b * 33 + (j - 1)) * FEAT + c;
        float4 v0 = *(const float4*)s, v1 = *(const float4*)(s + 4);
        ushort u[8] = {f2bf(v0.x), f2bf(v0.y), f2bf(v0.z), f2bf(v0.w),
                       f2bf(v1.x), f2bf(v1.y), f2bf(v1.z), f2bf(v1.w)};
        *(uint4*)dst = *(uint4*)u;
    }
}

// ---------------- fused GAT: scores + per-graph softmax + aggregation ----------------
// one block per graph; deterministic bucket order identical to previous 3-kernel chain
__global__ __launch_bounds__(256) void k_gat(const int* __restrict__ es, const int* __restrict__ ed,
                                             const float* __restrict__ z,
                                             const float* __restrict__ a_src,
                                             const float* __restrict__ a_dst,
                                             ushort* __restrict__ gnnB) {
    __shared__ float zt[NPG][520];                   // padded rows (70.7 KB)
    __shared__ float sps[NPG][NH], spd[NPG][NH], sm[NPG][NH], sden[NPG][NH];
    __shared__ float esc[EPG][NH];
    __shared__ int srcl[EPG], dll[EPG], order[EPG], cnt[NPG], bstart[NPG + 1];
    int b = blockIdx.x, t = threadIdx.x;
    // stage z [34][512] f32 (coalesced float4)
    for (int i = t; i < NPG * 128; i += 256) {
        int n = i >> 7, c4 = (i & 127) << 2;
        *(float4*)&zt[n][c4] = *(const float4*)&z[((size_t)b * NPG + n) * HA + c4];
    }
    for (int e = t; e < EPG; e += 256) {
        srcl[e] = es[b * EPG + e] - b * NPG;
        dll[e]  = ed[b * EPG + e] - b * NPG;
    }
    if (t < NPG) cnt[t] = 0;
    __syncthreads();
    // scores: one wave per node (shuffle-reduced), plus edge-count histogram
    {
        int wv = t >> 6, l = t & 63;
        for (int n = wv; n < NPG; n += 4) {
            float s[NH], d[NH];
#pragma unroll
            for (int i = 0; i < NH; i++) {
                float zv = zt[n][i * 64 + l];
                s[i] = zv * a_src[i * 64 + l];
                d[i] = zv * a_dst[i * 64 + l];
            }
#pragma unroll
            for (int i = 0; i < NH; i++) {
#pragma unroll
                for (int off = 32; off > 0; off >>= 1) {
                    s[i] += __shfl_xor(s[i], off);
                    d[i] += __shfl_xor(d[i], off);
                }
            }
            if (l == 0) {
#pragma unroll
                for (int i = 0; i < NH; i++) { sps[n][i] = s[i]; spd[n][i] = d[i]; }
            }
        }
    }
    for (int e = t; e < EPG; e += 256) atomicAdd(&cnt[dll[e]], 1);
    __syncthreads();
    if (t == 0) {   // deterministic serial prefix + scatter (ascending edge order)
        int s = 0;
        for (int n = 0; n < NPG; n++) { bstart[n] = s; s += cnt[n]; cnt[n] = bstart[n]; }
        bstart[NPG] = s;
        for (int e = 0; e < EPG; e++) order[cnt[dll[e]]++] = e;
    }
    __syncthreads();
    // edge scores (leaky relu)
    for (int i = t; i < EPG * NH; i += 256) {
        int e = i >> 3, h = i & 7;
        float sc = sps[srcl[e]][h] + spd[dll[e]][h];
        esc[e][h] = sc > 0.f ? sc : 0.2f * sc;
    }
    __syncthreads();
    // per-(node,head) max & denom over bucket (ascending edge order = bitwise stable)
    for (int i = t; i < NPG * NH; i += 256) {
        int n = i >> 3, h = i & 7;
        float m = -INFINITY;
        for (int j = bstart[n]; j < bstart[n + 1]; j++) m = fmaxf(m, esc[order[j]][h]);
        if (m == -INFINITY) m = 0.f;
        float den = 0.f;
        for (int j = bstart[n]; j < bstart[n + 1]; j++) den += expf(esc[order[j]][h] - m);
        sm[n][h] = m; sden[n][h] = den;
    }
    __syncthreads();
    // alpha in place
    for (int i = t; i < EPG * NH; i += 256) {
        int e = i >> 3, h = i & 7;
        esc[e][h] = expf(esc[e][h] - sm[dll[e]][h]) / (sden[dll[e]][h] + 1e-9f);
    }
    __syncthreads();
    // aggregation: thread handles (n, h, 8-wide d chunk) -> coalesced uint4 bf16 store
    for (int c = t; c < NPG * 64; c += 256) {
        int n = c >> 6, rem = c & 63, h = rem >> 3, d0 = (rem & 7) << 3;
        float acc[8] = {};
        for (int j = bstart[n]; j < bstart[n + 1]; j++) {
            int e = order[j];
            float a = esc[e][h];
            const float* zp = &zt[srcl[e]][h * 64 + d0];
#pragma unroll
            for (int q = 0; q < 8; q++) acc[q] = fmaf(a, zp[q], acc[q]);
        }
        ushort u[8];
#pragma unroll
        for (int q = 0; q < 8; q++) u[q] = f2bf(acc[q]);
        *(uint4*)&gnnB[((size_t)b * NPG + n) * HA + h * 64 + d0] = *(uint4*)u;
    }
}

extern "C" void kernel_launch(void* const* d_in, const int* in_sizes, int n_in,
                              void* d_out, int out_size, void* d_ws, size_t ws_size,
                              hipStream_t stream) {
    const float* locf  = (const float*)d_in[0];
    const float* gf    = (const float*)d_in[1];
    const int*   ei    = (const int*)d_in[2];
    const float* W1g   = (const float*)d_in[3];
    const float* b1g   = (const float*)d_in[4];
    const float* W2g   = (const float*)d_in[5];
    const float* b2g   = (const float*)d_in[6];
    const float* Wp    = (const float*)d_in[7];
    const float* bp    = (const float*)d_in[8];
    const float* Wg    = (const float*)d_in[9];
    const float* a_src = (const float*)d_in[10];
    const float* a_dst = (const float*)d_in[11];
    const float* Wllm  = (const float*)d_in[12];
    const float* bllm  = (const float*)d_in[13];
    float* out = (float*)d_out;
    float* ws  = (float*)d_ws;
    const int* es = ei;
    const int* ed = ei + NE;

    // d_out scratch layout (float offsets; every region dead before GEMM5 overwrite)
    float*  z      = out;                               // [0, 8,912,896)
    ushort* W1gT   = (ushort*)(out + 8912896);          // [8.9M, 34.1M) f — dead after GEMM1
    ushort* hB     = (ushort*)(out + 8912896);          // [8.9M, 17.8M) f — overlaps W1gT, written GEMM3
    ushort* poolB  = (ushort*)(out + 34078720);         // [34.1M, 40.4M) f
    float*  part1  = out + 40370176;                    // [40.4M, 57.1M) f (16 x 512x2048) — dead after red1
    ushort* nodesB = (ushort*)(out + 40370176);         // [40.4M, 50.4M) f — overlaps dead part1
    ushort* g1B    = (ushort*)(out + 57147392);         // [57.1M, 57.7M) f
    ushort* W2gT   = (ushort*)(out + 57671680);         // [57.7M, 58.9M) f
    ushort* WpT    = (ushort*)(out + 58851328);         // [58.9M, 59.4M) f
    ushort* WgT    = (ushort*)(out + 59441152);         // [59.4M, 59.7M) f
    ushort* outgB  = (ushort*)(out + 59703296);         // [59.7M, 60.0M) f
    float*  part2  = out + 59998208;                    // [60.0M, 62.4M) f (4 x 512x1152)
    // d_ws layout (22 MB; GEMM5 inputs live here, never in d_out)
    ushort* WllmT = (ushort*)ws;                        // 1,048,576 f
    ushort* gnnB  = (ushort*)(ws + 1048576);            // 4,456,448 f (ends 5,505,024 f)

    // fused transposes + pool
    k_prep<<<79744, 256, 0, stream>>>(W1g, W1gT, W2g, W2gT, Wp, WpT, Wg, WgT,
                                      Wllm, WllmT, gf, poolB);
    // GEMM1 (256sq 8-phase, split-K=16): [512,24576]x[24576,2048] -> f32 partials
    k_gemm256<true, false, false, false><<<dim3(8, 2, 16), 512, 0, stream>>>(
        poolB, W1gT, nullptr, part1, 512, GPD, C32, 1536);
    k_red<16, true><<<4096, 256, 0, stream>>>(part1, b1g, g1B, GPD, 1048576);
    // GEMM2 (128sq, split-K=4): [512,2048]x[2048,1152] -> partials; reduce + b2g
    k_gemm_bf<true, false, false, false><<<dim3(9, 4, 4), 256, 0, stream>>>(
        g1B, W2gT, nullptr, part2, 512, FEAT, GPD, 512);
    k_red<4, false><<<2304, 256, 0, stream>>>(part2, b2g, outgB, FEAT, 589824);
    // build node matrix
    k_nodes<<<9792, 256, 0, stream>>>(outgB, locf, nodesB);
    // GEMM3 (256sq): relu(nodes x Wp + bp) -> bf16 h [17408,1024]
    k_gemm256<false, true, true, true><<<dim3(4, 68), 512, 0, stream>>>(
        nodesB, WpT, bp, hB, NT, HID, FEAT, 0);
    // GEMM4 (256sq): z = h x Wg -> f32 [17408,512]
    k_gemm256<false, false, false, false><<<dim3(2, 68), 512, 0, stream>>>(
        hB, WgT, nullptr, z, NT, HA, HID, 0);
    // fused graph attention
    k_gat<<<BB, 256, 0, stream>>>(es, ed, z, a_src, a_dst, gnnB);
    // GEMM5 (256sq): out = gnn x Wllm + bllm -> f32 [17408,4096]
    k_gemm256<false, true, false, false><<<dim3(16, 68), 512, 0, stream>>>(
        gnnB, WllmT, bllm, out, NT, LLM, HA, 0);
}